// Round 20
// baseline (10568.800 us; speedup 1.0000x reference)
//
#include <hip/hip_runtime.h>

// Bit-matching XLA-CPU / Eigen SpatialConvolution, AVX-512 gebp (mr=48, nr=4):
//  - patch k-order: (kh SLOWEST, kw, ic FASTEST)  [ColMajor NHWC: k = ic + C*kw + 3C*kh]
//  - conv1: K=27 < kc => single flat FMA chain in that order (R4's conv1 — clean).
//  - conv2: K=576, kc = ((32768-768)/208) & ~7 = 152 => FOUR zero-initialized
//    panel chains k in [0,152),[152,304),[304,456),[456,576);
//    joined ((P0+P1)+P2)+P3 (sequential C += per panel), then bias.
//    (products are w*{0,1} => exact; only add structure matters)
//  - LIF f32 two-rounding (v + 0.5*(x-v)); contract(off); inv_tau=0.5 exact.
// Pipeline: conv1+LIF1 once (time-constant input) -> 5-bit masks; per t:
// conv2+LIF2 -> s2 bits; head 1x1 all t (sub-threshold rounding, order-safe).

#define NB    8
#define HW    128
#define NPIX  (HW*HW)          // 16384
#define NT    5

// ---------------- conv1 ((kh,kw,ic) flat FMA) + bias + 5-step LIF1 -> 5-bit mask
__global__ __launch_bounds__(256) void k_conv1_lif1(
    const float* __restrict__ lab, const float* __restrict__ W1,
    const float* __restrict__ b1, const float* __restrict__ tau1,
    unsigned char* __restrict__ s1bits)
{
#pragma clang fp contract(off)
    int g = blockIdx.x * 256 + threadIdx.x;      // (b,oc,y,x), exact grid
    int x = g & (HW - 1);
    int y = (g >> 7) & (HW - 1);
    int oc = (g >> 14) & 63;
    int b = g >> 20;

    const float* wbase = W1 + oc * 27;           // W1 [oc][ic][kh][kw]
    const float* ibase = lab + b * 3 * NPIX;     // lab [b][ic][y][x]
    float acc = 0.f;
    for (int kh = 0; kh < 3; ++kh) {             // kh SLOWEST
        int yy = y + kh - 1;
        if ((unsigned)yy >= (unsigned)HW) continue;
        for (int kw = 0; kw < 3; ++kw) {         // kw middle
            int xx = x + kw - 1;
            if ((unsigned)xx >= (unsigned)HW) continue;
            const float* px = ibase + yy * HW + xx;
#pragma unroll
            for (int ic = 0; ic < 3; ++ic) {     // ic FASTEST; flat FMA chain
                acc = __builtin_fmaf(wbase[ic * 9 + kh * 3 + kw], px[ic * NPIX], acc);
            }
        }
    }
    float xin = acc + b1[oc];                    // bias: separate add after conv

    float tauc = fminf(fmaxf(tau1[0], 0.5f), 5.0f);
    float it = 1.0f / tauc;

    float v = 0.f;
    unsigned bits = 0;
    for (int t = 0; t < NT; ++t) {
        float d = xin - v;                       // two-rounding LIF form
        float m = it * d;
        v = v + m;
        bool s = (v - 0.1f) >= 0.f;
        float vr = s ? 0.f : v;
        vr = fmaxf(vr, -2.f);
        vr = fminf(vr, 2.f);
        v = vr;
        if (s) bits |= (1u << t);
    }
    s1bits[g] = (unsigned char)bits;
}

// ---------------- conv2 ((kh,kw,ic), kc=152 four-panel) + LIF2 step -> s2 bit t
__global__ __launch_bounds__(256) void k_conv2_lif2(
    const unsigned char* __restrict__ s1, const float* __restrict__ W2,
    const float* __restrict__ b2, const float* __restrict__ tau2,
    float* __restrict__ v2, unsigned char* __restrict__ s2, int t)
{
#pragma clang fp contract(off)
    int g = blockIdx.x * 256 + threadIdx.x;      // (b,oc,y,x), exact grid
    int x = g & (HW - 1);
    int y = (g >> 7) & (HW - 1);
    int oc = (g >> 14) & 63;
    int b = g >> 20;

    const unsigned char* sb = s1 + b * 64 * NPIX;
    const float* wb = W2 + oc * 576;             // W2 [oc][ic][kh][kw]
    float a0 = 0.f, a1 = 0.f, a2 = 0.f, a3 = 0.f;
    int kbase = 0;                               // (kh*3+kw)*64
    for (int kh = 0; kh < 3; ++kh) {             // kh SLOWEST
        int yy = y + kh - 1;
        for (int kw = 0; kw < 3; ++kw, kbase += 64) {
            int xx = x + kw - 1;
            if ((unsigned)yy >= (unsigned)HW || (unsigned)xx >= (unsigned)HW) continue;
            const unsigned char* sp = sb + yy * HW + xx;
            const float* wk = wb + kh * 3 + kw;
            for (int ic = 0; ic < 64; ++ic) {    // ic FASTEST; products exact
                if ((sp[ic * NPIX] >> t) & 1) {
                    float w = wk[ic * 9];
                    int kk = kbase + ic;
                    if      (kk < 152) a0 = a0 + w;   // panel 0: [0,152)
                    else if (kk < 304) a1 = a1 + w;   // panel 1: [152,304)
                    else if (kk < 456) a2 = a2 + w;   // panel 2: [304,456)
                    else               a3 = a3 + w;   // panel 3: [456,576)
                }
            }
        }
    }
    float x2 = (((a0 + a1) + a2) + a3) + b2[oc]; // sequential C += joins, then bias

    float tauc = fminf(fmaxf(tau2[0], 0.5f), 5.0f);
    float it = 1.0f / tauc;

    float v = t ? v2[g] : 0.f;
    float d = x2 - v;
    float m = it * d;
    v = v + m;
    bool s = (v - 0.1f) >= 0.f;
    float vr = s ? 0.f : v;
    vr = fmaxf(vr, -2.f);
    vr = fminf(vr, 2.f);
    v2[g] = vr;

    unsigned char prev = t ? s2[g] : (unsigned char)0;
    s2[g] = (unsigned char)(prev | ((unsigned)s << t));
}

// ---------------- head conv 1x1 (f32), all t at once
__global__ __launch_bounds__(256) void k_head(
    const unsigned char* __restrict__ s2, const float* __restrict__ Wh,
    const float* __restrict__ bh, float* __restrict__ out)
{
#pragma clang fp contract(off)
    int g = blockIdx.x * 256 + threadIdx.x;      // (t,b,c,y,x), exact grid
    int px = g & (NPIX - 1);
    int c  = (g >> 14) % 3;
    int b  = (g / (3 * NPIX)) & (NB - 1);
    int t  = g / (3 * NPIX * NB);

    const unsigned char* sp = s2 + b * 64 * NPIX + px;
    float acc = 0.f;
    for (int oc = 0; oc < 64; ++oc) {            // exact products; sub-threshold only
        if ((sp[oc * NPIX] >> t) & 1) acc = acc + Wh[c * 64 + oc];
    }
    out[g] = acc + bh[c];
}

extern "C" void kernel_launch(void* const* d_in, const int* in_sizes, int n_in,
                              void* d_out, int out_size, void* d_ws, size_t ws_size,
                              hipStream_t stream) {
    const float* lab  = (const float*)d_in[0];
    const float* W1   = (const float*)d_in[1];
    const float* b1   = (const float*)d_in[2];
    const float* tau1 = (const float*)d_in[3];
    const float* W2   = (const float*)d_in[4];
    const float* b2   = (const float*)d_in[5];
    const float* tau2 = (const float*)d_in[6];
    const float* Wh   = (const float*)d_in[7];
    const float* bh   = (const float*)d_in[8];
    float* out = (float*)d_out;

    // ws: s1 bits 8 MiB | v2 f32 32 MiB | s2 bits 8 MiB
    const size_t SZ_S1 = (size_t)NB * 64 * NPIX;             //  8,388,608
    const size_t SZ_V2 = (size_t)NB * 64 * NPIX * 4;         // 33,554,432
    const size_t SZ_S2 = (size_t)NB * 64 * NPIX;             //  8,388,608
    if (ws_size < SZ_S1 + SZ_V2 + SZ_S2) return;

    char* ws = (char*)d_ws;
    unsigned char* s1 = (unsigned char*)ws;
    float* v2         = (float*)(ws + SZ_S1);
    unsigned char* s2 = (unsigned char*)(ws + SZ_S1 + SZ_V2);

    const int n_elem = NB * 64 * NPIX;           // 8,388,608
    hipLaunchKernelGGL(k_conv1_lif1, dim3(n_elem / 256), dim3(256), 0, stream,
                       lab, W1, b1, tau1, s1);
    for (int t = 0; t < NT; ++t) {
        hipLaunchKernelGGL(k_conv2_lif2, dim3(n_elem / 256), dim3(256), 0, stream,
                           s1, W2, b2, tau2, v2, s2, t);
    }
    hipLaunchKernelGGL(k_head, dim3(NT * NB * 3 * NPIX / 256), dim3(256), 0, stream,
                       s2, Wh, bh, out);
}

// Round 21
// 3190.193 us; speedup vs baseline: 3.3129x; 3.3129x over previous
//
#include <hip/hip_runtime.h>

// Numerics frozen from R20 (PASSED, absmax 0.0039):
//  conv1: (kh,kw,ic) flat FMA chain; conv2: (kh,kw,ic) with 4 panel chains
//  split at k=152/304/456, joined ((P0+P1)+P2)+P3 then bias; LIF f32
//  two-rounding v+0.5*(x-v); head: ascending-oc sequential chain per c.
// This round: same arithmetic, fast structure.
//  - conv1 packs spike bits via __ballot -> smask[b][t][y][x] (u64, bit=ic)
//  - conv2: wave = 8-px strip x 64 oc (lane=oc), all 5 t in-register
//    (v2 state in VGPRs), weights transposed Wt[tap][ic][oc] (coalesced),
//    term = bfe + select(acc+w, acc) — acc EXACTLY unchanged when bit clear.
//  - head reads packed s2 masks; same ascending-oc chains.

#define NB    8
#define HW    128
#define NPIX  (HW*HW)          // 16384
#define NT    5

// ---------------- W2 [oc][ic][tap] -> Wt [tap][ic][oc]
__global__ void k_transpose_w2(const float* __restrict__ W2, float* __restrict__ Wt) {
    int i = blockIdx.x * 256 + threadIdx.x;      // 36864
    if (i >= 9 * 64 * 64) return;
    int oc = i & 63;
    int ic = (i >> 6) & 63;
    int tap = i >> 12;
    Wt[i] = W2[(oc * 64 + ic) * 9 + tap];
}

// ---------------- conv1 ((kh,kw,ic) flat FMA) + LIF1 -> ballot-packed masks
__global__ __launch_bounds__(256) void k_conv1_lif1(
    const float* __restrict__ lab, const float* __restrict__ W1,
    const float* __restrict__ b1, const float* __restrict__ tau1,
    unsigned long long* __restrict__ smask)
{
#pragma clang fp contract(off)
    __shared__ float w1s[64 * 27];
    __shared__ float b1s[64];
    {
        int tid = threadIdx.x;
        for (int e = tid; e < 64 * 27; e += 256) w1s[e] = W1[e];
        if (tid < 64) b1s[tid] = b1[tid];
        __syncthreads();
    }
    int g = blockIdx.x * 256 + threadIdx.x;      // (b,y,x,oc) — lane = oc
    int oc = g & 63;
    int x = (g >> 6) & (HW - 1);
    int y = (g >> 13) & (HW - 1);
    int b = g >> 20;

    const float* wbase = w1s + oc * 27;          // same values as W1[oc][..]
    const float* ibase = lab + b * 3 * NPIX;
    float acc = 0.f;
    for (int kh = 0; kh < 3; ++kh) {             // identical chain to R20
        int yy = y + kh - 1;
        if ((unsigned)yy >= (unsigned)HW) continue;
        for (int kw = 0; kw < 3; ++kw) {
            int xx = x + kw - 1;
            if ((unsigned)xx >= (unsigned)HW) continue;
            const float* px = ibase + yy * HW + xx;
#pragma unroll
            for (int ic = 0; ic < 3; ++ic) {
                acc = __builtin_fmaf(wbase[ic * 9 + kh * 3 + kw], px[ic * NPIX], acc);
            }
        }
    }
    float xin = acc + b1s[oc];

    float tauc = fminf(fmaxf(tau1[0], 0.5f), 5.0f);
    float it = 1.0f / tauc;

    float v = 0.f;
    unsigned bits = 0;
    for (int t = 0; t < NT; ++t) {
        float d = xin - v;
        float m = it * d;
        v = v + m;
        bool s = (v - 0.1f) >= 0.f;
        float vr = s ? 0.f : v;
        vr = fmaxf(vr, -2.f);
        vr = fminf(vr, 2.f);
        v = vr;
        if (s) bits |= (1u << t);
    }
    // pack: bit oc of smask[b][t][y][x]
    for (int t = 0; t < NT; ++t) {
        unsigned long long bal = __ballot((bits >> t) & 1);
        if (oc == 0) smask[((size_t)(b * NT + t) * NPIX) + y * HW + x] = bal;
    }
}

// ---------------- conv2 (packed, all t) + LIF2 -> s2 masks
// wave = strip of 8 pixels (y, x0..x0+7), lane = oc. 4 waves/block.
#define SEG(IC0, IC1, M, SH, PN)                                   \
    for (int ic = IC0; ic < IC1; ++ic) {                           \
        float w = wt[ic * 64];                                     \
        _Pragma("unroll")                                          \
        for (int p = 0; p < 8; ++p) {                              \
            if ((M[p] >> (ic - SH)) & 1u) acc[p][PN] = acc[p][PN] + w; \
        }                                                          \
    }

#define TAP(KH, KW, SEGS) {                                        \
    const int yy = y + KH - 1;                                     \
    const bool vy = (unsigned)yy < (unsigned)HW;                   \
    unsigned Mlo[8], Mhi[8];                                       \
    _Pragma("unroll")                                              \
    for (int p = 0; p < 8; ++p) {                                  \
        int xx = x0 + KW - 1 + p;                                  \
        unsigned long long mm = (vy && (unsigned)xx < (unsigned)HW) \
                                ? smb[yy * HW + xx] : 0ULL;        \
        Mlo[p] = (unsigned)mm; Mhi[p] = (unsigned)(mm >> 32);      \
    }                                                              \
    const float* wt = Wt + (KH * 3 + KW) * 4096 + oc;              \
    SEGS }

__global__ __launch_bounds__(256) void k_conv2_lif2(
    const unsigned long long* __restrict__ smask,
    const float* __restrict__ Wt, const float* __restrict__ b2,
    const float* __restrict__ tau2, unsigned long long* __restrict__ s2m)
{
#pragma clang fp contract(off)
    const int tid = threadIdx.x;
    const int oc = tid & 63;
    const int wid = blockIdx.x * 4 + (tid >> 6);   // 16384 strips
    const int b = wid >> 11;
    const int rem = wid & 2047;
    const int y = rem >> 4;
    const int x0 = (rem & 15) * 8;

    const float b2oc = b2[oc];
    float tauc = fminf(fmaxf(tau2[0], 0.5f), 5.0f);
    const float it = 1.0f / tauc;

    float v[8];
    for (int t = 0; t < NT; ++t) {
        float acc[8][4];
#pragma unroll
        for (int p = 0; p < 8; ++p) {
            acc[p][0] = 0.f; acc[p][1] = 0.f; acc[p][2] = 0.f; acc[p][3] = 0.f;
        }
        const unsigned long long* smb = smask + (size_t)(b * NT + t) * NPIX;

        // taps in (kh,kw) order; ic ascending; panels split at k=152/304/456
        TAP(0, 0, SEG(0,32,Mlo,0,0)  SEG(32,64,Mhi,32,0))
        TAP(0, 1, SEG(0,32,Mlo,0,0)  SEG(32,64,Mhi,32,0))
        TAP(0, 2, SEG(0,24,Mlo,0,0)  SEG(24,32,Mlo,0,1)  SEG(32,64,Mhi,32,1))
        TAP(1, 0, SEG(0,32,Mlo,0,1)  SEG(32,64,Mhi,32,1))
        TAP(1, 1, SEG(0,32,Mlo,0,1)  SEG(32,48,Mhi,32,1) SEG(48,64,Mhi,32,2))
        TAP(1, 2, SEG(0,32,Mlo,0,2)  SEG(32,64,Mhi,32,2))
        TAP(2, 0, SEG(0,32,Mlo,0,2)  SEG(32,64,Mhi,32,2))
        TAP(2, 1, SEG(0,8,Mlo,0,2)   SEG(8,32,Mlo,0,3)   SEG(32,64,Mhi,32,3))
        TAP(2, 2, SEG(0,32,Mlo,0,3)  SEG(32,64,Mhi,32,3))

        unsigned long long* s2mb = s2m + (size_t)(b * NT + t) * NPIX;
#pragma unroll
        for (int p = 0; p < 8; ++p) {
            float x2 = (((acc[p][0] + acc[p][1]) + acc[p][2]) + acc[p][3]) + b2oc;
            float vp = (t == 0) ? 0.f : v[p];
            float d = x2 - vp;
            float m = it * d;
            vp = vp + m;
            bool s = (vp - 0.1f) >= 0.f;
            float vr = s ? 0.f : vp;
            vr = fmaxf(vr, -2.f);
            vr = fminf(vr, 2.f);
            v[p] = vr;
            unsigned long long bal = __ballot(s);
            if (oc == 0) s2mb[y * HW + x0 + p] = bal;
        }
    }
}

// ---------------- head 1x1 from packed s2 masks
__global__ __launch_bounds__(256) void k_head(
    const unsigned long long* __restrict__ s2m, const float* __restrict__ Wh,
    const float* __restrict__ bh, float* __restrict__ out)
{
#pragma clang fp contract(off)
    __shared__ float whs[192];
    __shared__ float bhs[3];
    {
        int tid = threadIdx.x;
        if (tid < 192) whs[tid] = Wh[tid];
        if (tid < 3) bhs[tid] = bh[tid];
        __syncthreads();
    }
    int g = blockIdx.x * 256 + threadIdx.x;      // (t,b,px): 5*8*16384
    int px = g & (NPIX - 1);
    int r = g >> 14;
    int b = r & 7;
    int t = r >> 3;

    unsigned long long m = s2m[(size_t)(b * NT + t) * NPIX + px];
    unsigned mlo = (unsigned)m, mhi = (unsigned)(m >> 32);
    float c0 = 0.f, c1 = 0.f, c2 = 0.f;
    for (int oc = 0; oc < 32; ++oc) {            // ascending oc — same chain as R20
        unsigned bit = (mlo >> oc) & 1u;
        if (bit) { c0 = c0 + whs[oc]; c1 = c1 + whs[64 + oc]; c2 = c2 + whs[128 + oc]; }
    }
    for (int oc = 32; oc < 64; ++oc) {
        unsigned bit = (mhi >> (oc - 32)) & 1u;
        if (bit) { c0 = c0 + whs[oc]; c1 = c1 + whs[64 + oc]; c2 = c2 + whs[128 + oc]; }
    }
    int obase = ((t * NB + b) * 3) * NPIX + px;
    out[obase] = c0 + bhs[0];
    out[obase + NPIX] = c1 + bhs[1];
    out[obase + 2 * NPIX] = c2 + bhs[2];
}

extern "C" void kernel_launch(void* const* d_in, const int* in_sizes, int n_in,
                              void* d_out, int out_size, void* d_ws, size_t ws_size,
                              hipStream_t stream) {
    const float* lab  = (const float*)d_in[0];
    const float* W1   = (const float*)d_in[1];
    const float* b1   = (const float*)d_in[2];
    const float* tau1 = (const float*)d_in[3];
    const float* W2   = (const float*)d_in[4];
    const float* b2   = (const float*)d_in[5];
    const float* tau2 = (const float*)d_in[6];
    const float* Wh   = (const float*)d_in[7];
    const float* bh   = (const float*)d_in[8];
    float* out = (float*)d_out;

    // ws: smask 5.25MB | s2mask 5.25MB | Wt 147KB
    const size_t SZ_SM = (size_t)NB * NT * NPIX * 8;         // 5,242,880
    const size_t SZ_WT = 9 * 64 * 64 * 4;                    //   147,456
    if (ws_size < 2 * SZ_SM + SZ_WT) return;

    char* ws = (char*)d_ws;
    unsigned long long* smask = (unsigned long long*)ws;
    unsigned long long* s2m   = (unsigned long long*)(ws + SZ_SM);
    float* Wt                 = (float*)(ws + 2 * SZ_SM);

    hipLaunchKernelGGL(k_transpose_w2, dim3(144), dim3(256), 0, stream, W2, Wt);
    hipLaunchKernelGGL(k_conv1_lif1, dim3(NB * 64 * NPIX / 256), dim3(256), 0, stream,
                       lab, W1, b1, tau1, smask);
    hipLaunchKernelGGL(k_conv2_lif2, dim3(4096), dim3(256), 0, stream,
                       smask, Wt, b2, tau2, s2m);
    hipLaunchKernelGGL(k_head, dim3(NT * NB * NPIX / 256), dim3(256), 0, stream,
                       s2m, Wh, bh, out);
}

// Round 22
// 2487.743 us; speedup vs baseline: 4.2483x; 1.2824x over previous
//
#include <hip/hip_runtime.h>

// Numerics frozen from R20 (PASSED, absmax 0.0039):
//  conv1: (kh,kw,ic) flat FMA chain; conv2: (kh,kw,ic) with 4 panel chains
//  split at k=152/304/456, joined ((P0+P1)+P2)+P3 then bias; LIF f32
//  two-rounding v+0.5*(x-v); head: ascending-oc sequential chain per c.
// R22 changes (bit-exact, structure only):
//  - conv2 wave id readfirstlane'd -> strip coords uniform-provable ->
//    mask loads become SMEM/SGPR, bit tests become SALU.
//  - branchless select: acc += as_float(wbits & -bit)  (adds w or +0.0;
//    +0.0 add is exact-identical to skipping — acc never holds -0.0).

#define NB    8
#define HW    128
#define NPIX  (HW*HW)          // 16384
#define NT    5

// ---------------- W2 [oc][ic][tap] -> Wt [tap][ic][oc]
__global__ void k_transpose_w2(const float* __restrict__ W2, float* __restrict__ Wt) {
    int i = blockIdx.x * 256 + threadIdx.x;      // 36864
    if (i >= 9 * 64 * 64) return;
    int oc = i & 63;
    int ic = (i >> 6) & 63;
    int tap = i >> 12;
    Wt[i] = W2[(oc * 64 + ic) * 9 + tap];
}

// ---------------- conv1 ((kh,kw,ic) flat FMA) + LIF1 -> ballot-packed masks
__global__ __launch_bounds__(256) void k_conv1_lif1(
    const float* __restrict__ lab, const float* __restrict__ W1,
    const float* __restrict__ b1, const float* __restrict__ tau1,
    unsigned long long* __restrict__ smask)
{
#pragma clang fp contract(off)
    __shared__ float w1s[64 * 27];
    __shared__ float b1s[64];
    {
        int tid = threadIdx.x;
        for (int e = tid; e < 64 * 27; e += 256) w1s[e] = W1[e];
        if (tid < 64) b1s[tid] = b1[tid];
        __syncthreads();
    }
    int g = blockIdx.x * 256 + threadIdx.x;      // (b,y,x,oc) — lane = oc
    int oc = g & 63;
    int x = (g >> 6) & (HW - 1);
    int y = (g >> 13) & (HW - 1);
    int b = g >> 20;

    const float* wbase = w1s + oc * 27;
    const float* ibase = lab + b * 3 * NPIX;
    float acc = 0.f;
    for (int kh = 0; kh < 3; ++kh) {             // identical chain to R20
        int yy = y + kh - 1;
        if ((unsigned)yy >= (unsigned)HW) continue;
        for (int kw = 0; kw < 3; ++kw) {
            int xx = x + kw - 1;
            if ((unsigned)xx >= (unsigned)HW) continue;
            const float* px = ibase + yy * HW + xx;
#pragma unroll
            for (int ic = 0; ic < 3; ++ic) {
                acc = __builtin_fmaf(wbase[ic * 9 + kh * 3 + kw], px[ic * NPIX], acc);
            }
        }
    }
    float xin = acc + b1s[oc];

    float tauc = fminf(fmaxf(tau1[0], 0.5f), 5.0f);
    float it = 1.0f / tauc;

    float v = 0.f;
    unsigned bits = 0;
    for (int t = 0; t < NT; ++t) {
        float d = xin - v;
        float m = it * d;
        v = v + m;
        bool s = (v - 0.1f) >= 0.f;
        float vr = s ? 0.f : v;
        vr = fmaxf(vr, -2.f);
        vr = fminf(vr, 2.f);
        v = vr;
        if (s) bits |= (1u << t);
    }
    for (int t = 0; t < NT; ++t) {
        unsigned long long bal = __ballot((bits >> t) & 1);
        if (oc == 0) smask[((size_t)(b * NT + t) * NPIX) + y * HW + x] = bal;
    }
}

// ---------------- conv2 (packed, all t) + LIF2 -> s2 masks
// wave = strip of 8 pixels (y, x0..x0+7), lane = oc. Masks are wave-uniform
// (SGPR); select is branchless AND with sign-extended bit.
#define SEG(IC0, IC1, M, SH, PN)                                        \
    for (int ic = IC0; ic < IC1; ++ic) {                                \
        unsigned wb = wtu[ic * 64];                                     \
        _Pragma("unroll")                                               \
        for (int p = 0; p < 8; ++p) {                                   \
            unsigned sel = wb & (unsigned)(-(int)((M[p] >> (ic - SH)) & 1u)); \
            acc[p][PN] = acc[p][PN] + __uint_as_float(sel);             \
        }                                                               \
    }

#define TAP(KH, KW, SEGS) {                                             \
    const int yy = y + KH - 1;                                          \
    const bool vy = (unsigned)yy < (unsigned)HW;                        \
    unsigned Mlo[8], Mhi[8];                                            \
    _Pragma("unroll")                                                   \
    for (int p = 0; p < 8; ++p) {                                       \
        int xx = x0 + KW - 1 + p;                                       \
        unsigned long long mm = (vy && (unsigned)xx < (unsigned)HW)     \
                                ? smb[yy * HW + xx] : 0ULL;             \
        Mlo[p] = (unsigned)mm; Mhi[p] = (unsigned)(mm >> 32);           \
    }                                                                   \
    const unsigned* wtu = (const unsigned*)(Wt + (KH * 3 + KW) * 4096) + oc; \
    SEGS }

__global__ __launch_bounds__(256) void k_conv2_lif2(
    const unsigned long long* __restrict__ smask,
    const float* __restrict__ Wt, const float* __restrict__ b2,
    const float* __restrict__ tau2, unsigned long long* __restrict__ s2m)
{
#pragma clang fp contract(off)
    const int tid = threadIdx.x;
    const int oc = tid & 63;
    // readfirstlane -> wave-uniform provable -> scalar mask loads + SALU tests
    const int wid = __builtin_amdgcn_readfirstlane(blockIdx.x * 4 + (tid >> 6));
    const int b = wid >> 11;
    const int rem = wid & 2047;
    const int y = rem >> 4;
    const int x0 = (rem & 15) * 8;

    const float b2oc = b2[oc];
    float tauc = fminf(fmaxf(tau2[0], 0.5f), 5.0f);
    const float it = 1.0f / tauc;

    float v[8];
    for (int t = 0; t < NT; ++t) {
        float acc[8][4];
#pragma unroll
        for (int p = 0; p < 8; ++p) {
            acc[p][0] = 0.f; acc[p][1] = 0.f; acc[p][2] = 0.f; acc[p][3] = 0.f;
        }
        const unsigned long long* smb = smask + (size_t)(b * NT + t) * NPIX;

        // taps in (kh,kw) order; ic ascending; panels split at k=152/304/456
        TAP(0, 0, SEG(0,32,Mlo,0,0)  SEG(32,64,Mhi,32,0))
        TAP(0, 1, SEG(0,32,Mlo,0,0)  SEG(32,64,Mhi,32,0))
        TAP(0, 2, SEG(0,24,Mlo,0,0)  SEG(24,32,Mlo,0,1)  SEG(32,64,Mhi,32,1))
        TAP(1, 0, SEG(0,32,Mlo,0,1)  SEG(32,64,Mhi,32,1))
        TAP(1, 1, SEG(0,32,Mlo,0,1)  SEG(32,48,Mhi,32,1) SEG(48,64,Mhi,32,2))
        TAP(1, 2, SEG(0,32,Mlo,0,2)  SEG(32,64,Mhi,32,2))
        TAP(2, 0, SEG(0,32,Mlo,0,2)  SEG(32,64,Mhi,32,2))
        TAP(2, 1, SEG(0,8,Mlo,0,2)   SEG(8,32,Mlo,0,3)   SEG(32,64,Mhi,32,3))
        TAP(2, 2, SEG(0,32,Mlo,0,3)  SEG(32,64,Mhi,32,3))

        unsigned long long* s2mb = s2m + (size_t)(b * NT + t) * NPIX;
#pragma unroll
        for (int p = 0; p < 8; ++p) {
            float x2 = (((acc[p][0] + acc[p][1]) + acc[p][2]) + acc[p][3]) + b2oc;
            float vp = (t == 0) ? 0.f : v[p];
            float d = x2 - vp;
            float m = it * d;
            vp = vp + m;
            bool s = (vp - 0.1f) >= 0.f;
            float vr = s ? 0.f : vp;
            vr = fmaxf(vr, -2.f);
            vr = fminf(vr, 2.f);
            v[p] = vr;
            unsigned long long bal = __ballot(s);
            if (oc == 0) s2mb[y * HW + x0 + p] = bal;
        }
    }
}

// ---------------- head 1x1 from packed s2 masks
__global__ __launch_bounds__(256) void k_head(
    const unsigned long long* __restrict__ s2m, const float* __restrict__ Wh,
    const float* __restrict__ bh, float* __restrict__ out)
{
#pragma clang fp contract(off)
    __shared__ float whs[192];
    __shared__ float bhs[3];
    {
        int tid = threadIdx.x;
        if (tid < 192) whs[tid] = Wh[tid];
        if (tid < 3) bhs[tid] = bh[tid];
        __syncthreads();
    }
    int g = blockIdx.x * 256 + threadIdx.x;      // (t,b,px): 5*8*16384
    int px = g & (NPIX - 1);
    int r = g >> 14;
    int b = r & 7;
    int t = r >> 3;

    unsigned long long m = s2m[(size_t)(b * NT + t) * NPIX + px];
    unsigned mlo = (unsigned)m, mhi = (unsigned)(m >> 32);
    float c0 = 0.f, c1 = 0.f, c2 = 0.f;
    for (int oc = 0; oc < 32; ++oc) {            // ascending oc — frozen chain
        unsigned bit = (mlo >> oc) & 1u;
        if (bit) { c0 = c0 + whs[oc]; c1 = c1 + whs[64 + oc]; c2 = c2 + whs[128 + oc]; }
    }
    for (int oc = 32; oc < 64; ++oc) {
        unsigned bit = (mhi >> (oc - 32)) & 1u;
        if (bit) { c0 = c0 + whs[oc]; c1 = c1 + whs[64 + oc]; c2 = c2 + whs[128 + oc]; }
    }
    int obase = ((t * NB + b) * 3) * NPIX + px;
    out[obase] = c0 + bhs[0];
    out[obase + NPIX] = c1 + bhs[1];
    out[obase + 2 * NPIX] = c2 + bhs[2];
}

extern "C" void kernel_launch(void* const* d_in, const int* in_sizes, int n_in,
                              void* d_out, int out_size, void* d_ws, size_t ws_size,
                              hipStream_t stream) {
    const float* lab  = (const float*)d_in[0];
    const float* W1   = (const float*)d_in[1];
    const float* b1   = (const float*)d_in[2];
    const float* tau1 = (const float*)d_in[3];
    const float* W2   = (const float*)d_in[4];
    const float* b2   = (const float*)d_in[5];
    const float* tau2 = (const float*)d_in[6];
    const float* Wh   = (const float*)d_in[7];
    const float* bh   = (const float*)d_in[8];
    float* out = (float*)d_out;

    // ws: smask 5.25MB | s2mask 5.25MB | Wt 147KB
    const size_t SZ_SM = (size_t)NB * NT * NPIX * 8;         // 5,242,880
    const size_t SZ_WT = 9 * 64 * 64 * 4;                    //   147,456
    if (ws_size < 2 * SZ_SM + SZ_WT) return;

    char* ws = (char*)d_ws;
    unsigned long long* smask = (unsigned long long*)ws;
    unsigned long long* s2m   = (unsigned long long*)(ws + SZ_SM);
    float* Wt                 = (float*)(ws + 2 * SZ_SM);

    hipLaunchKernelGGL(k_transpose_w2, dim3(144), dim3(256), 0, stream, W2, Wt);
    hipLaunchKernelGGL(k_conv1_lif1, dim3(NB * 64 * NPIX / 256), dim3(256), 0, stream,
                       lab, W1, b1, tau1, smask);
    hipLaunchKernelGGL(k_conv2_lif2, dim3(4096), dim3(256), 0, stream,
                       smask, Wt, b2, tau2, s2m);
    hipLaunchKernelGGL(k_head, dim3(NT * NB * NPIX / 256), dim3(256), 0, stream,
                       s2m, Wh, bh, out);
}